// Round 4
// baseline (428.153 us; speedup 1.0000x reference)
//
#include <hip/hip_runtime.h>
#include <stdint.h>

#define B_   8
#define N_   256
#define D_   128
#define MID_ 128
#define FEAT_ 256

typedef __attribute__((ext_vector_type(4))) float  floatx4;
typedef __attribute__((ext_vector_type(4))) int    intx4;
typedef __attribute__((ext_vector_type(8))) __bf16 bf16x8;

__device__ __forceinline__ floatx4 mfma16(bf16x8 a, bf16x8 b, floatx4 c) {
    return __builtin_amdgcn_mfma_f32_16x16x32_bf16(a, b, c, 0, 0, 0);
}

// HW bf16 convert (compiler emits v_cvt_pk_bf16_f32 on gfx950), RNE.
__device__ __forceinline__ bf16x8 cvt8(floatx4 a, floatx4 b) {
    bf16x8 r;
    r[0] = (__bf16)a[0]; r[1] = (__bf16)a[1]; r[2] = (__bf16)a[2]; r[3] = (__bf16)a[3];
    r[4] = (__bf16)b[0]; r[5] = (__bf16)b[1]; r[6] = (__bf16)b[2]; r[7] = (__bf16)b[3];
    return r;
}

// ---------------- kernel W: pre-swizzle all weights to bf16 LDS-image layout ----------------
// dst elem index for (k,m): (((k>>5)*8+(m>>4))*64 + ((k>>3)&3)*16 + (m&15))*8 + (k&7)
// Each thread: 8 coalesced f32 loads (j = k&7), one contiguous 16-B bf16x8 store.
__global__ void __launch_bounds__(256)
kW(const float* __restrict__ W1, const float* __restrict__ W2,
   const float* __restrict__ Wo1, const float* __restrict__ We,
   __bf16* __restrict__ dst) {
    int t = threadIdx.x;
    int g = blockIdx.x * 2 + (t >> 7);   // global k-group 0..111
    int m = t & 127;
    const float* src; int kg; int off;
    if (g < 32)      { src = W1;  kg = g;      off = 0; }
    else if (g < 64) { src = W2;  kg = g - 32; off = 32768; }
    else if (g < 96) { src = Wo1; kg = g - 64; off = 65536; }
    else             { src = We;  kg = g - 96; off = 98304; }
    bf16x8 r;
#pragma unroll
    for (int jv = 0; jv < 8; ++jv) r[jv] = (__bf16)src[(kg * 8 + jv) * MID_ + m];
    int base = (((kg >> 2) * 8 + (m >> 4)) * 64 + (kg & 3) * 16 + (m & 15)) * 8;
    *(bf16x8*)&dst[off + base] = r;
}

// ---------------- kernel A: per-node GEMMs via MFMA (bf16) + fused gplus ----------------
// grid (32 row-tiles of 64, 3 weights). A = W^T (pre-swizzled, vector-copied to LDS).
// wid 0: C = feat@W1 + (g@Wg+bg+b1+be) ; wid 1: msg2 = feat@W2 + b2 ; wid 2: retA = feat@Wo1+bo1+bo2
__global__ void __launch_bounds__(256)
kA(const float* __restrict__ nfeat, const float* __restrict__ hidden,
   const __bf16* __restrict__ Wpre,
   const float* __restrict__ g, const float* __restrict__ Wg,
   const float* __restrict__ bg, const float* __restrict__ b1,
   const float* __restrict__ be, const float* __restrict__ b2,
   const float* __restrict__ bo1, const float* __restrict__ bo2,
   float* __restrict__ C, float* __restrict__ msg2, float* __restrict__ retA) {
    __shared__ __bf16 Wb[8 * 8 * 64 * 8];   // [ks][mt][lane][jj], 64 KB
    __shared__ float gp_part[2][MID_];
    __shared__ float gp_sh[MID_];
    int t = threadIdx.x;
    int wid = blockIdx.y;
    // vector copy of pre-swizzled bf16 weights: 4096 x 16 B
    {
        const intx4* srcW = (const intx4*)(Wpre + (size_t)wid * 32768);
        intx4* dstW = (intx4*)Wb;
#pragma unroll
        for (int it = 0; it < 16; ++it) dstW[t + it * 256] = srcW[t + it * 256];
    }
    // fused kG: gplus[b] = g[b]@Wg + bg + b1 + be  (block-uniform batch, split-k halves)
    int bblk = blockIdx.x >> 2;             // 4 row-tiles per batch
    if (wid == 0) {
        int m = t & 127, h = t >> 7;
        const float* gr = g + bblk * D_;
        float a = 0.f;
        for (int k = h * 64; k < h * 64 + 64; ++k)
            a += gr[k] * Wg[k * MID_ + m];
        gp_part[h][m] = a;
    }
    __syncthreads();
    if (wid == 0 && t < 128)
        gp_sh[t] = gp_part[0][t] + gp_part[1][t] + bg[t] + b1[t] + be[t];
    __syncthreads();

    int lane = t & 63, w = t >> 6;
    int n16 = lane & 15, quad = lane >> 4;
    int R = blockIdx.x * 64 + w * 16 + n16;   // feat row (tile never crosses batch)
    const float* frow0 = nfeat  + (size_t)R * D_ + quad * 8;
    const float* frow1 = hidden + (size_t)R * D_ + quad * 8;

    bf16x8 bfrag[8];
#pragma unroll
    for (int ks = 0; ks < 8; ++ks) {
        const float* p = (ks < 4) ? (frow0 + ks * 32) : (frow1 + (ks - 4) * 32);
        floatx4 v0 = *(const floatx4*)p;
        floatx4 v1 = *(const floatx4*)(p + 4);
        bfrag[ks] = cvt8(v0, v1);
    }

    float* outp = (wid == 0) ? C : ((wid == 1) ? msg2 : retA);
#pragma unroll 2
    for (int mt = 0; mt < 8; ++mt) {
        floatx4 acc = (floatx4)0.f;
#pragma unroll
        for (int ks = 0; ks < 8; ++ks) {
            bf16x8 a = *(const bf16x8*)&Wb[((ks * 8 + mt) * 64 + lane) * 8];
            acc = mfma16(a, bfrag[ks], acc);
        }
        int m0 = mt * 16 + quad * 4;
        floatx4 add;
        if (wid == 0)      add = *(const floatx4*)&gp_sh[m0];
        else if (wid == 1) add = *(const floatx4*)&b2[m0];
        else {
            floatx4 x = *(const floatx4*)&bo1[m0];
            floatx4 y = *(const floatx4*)&bo2[m0];
            add = x + y;
        }
        *(floatx4*)&outp[(size_t)R * MID_ + m0] = acc + add;
    }
}

// ---------------- kernel B: fused msg_e GEMM + broadcast-add + mask-max + out ----------------
// one block per (b, j-pair). adj is {0,1}: compact active-i list, load/compute only those
// e-rows. Chunks are processed in PAIRS (c, c+4) so each Wb ds_read feeds 2 MFMAs.
// Padding slots contribute exact 0 (legal when nact<256; fmax(mx,0) covers the rest).
__global__ void __launch_bounds__(256, 4)
kB(const float* __restrict__ e, const __bf16* __restrict__ Wes,
   const float* __restrict__ adj, const float* __restrict__ C,
   const float* __restrict__ msg2, const float* __restrict__ retA,
   const float* __restrict__ Wo2, float* __restrict__ out) {
    __shared__ __bf16 Wb[4 * 8 * 64 * 8];   // [ks][mt][lane][jj], 32 KB
    __shared__ float C_sh[MID_];
    __shared__ float wmax[4][MID_];
    __shared__ float msgs_sh[MID_];
    __shared__ float part[2][MID_];
    __shared__ unsigned short list_sh[N_];
    __shared__ float aval_sh[N_];
    __shared__ int wcnt[4];

    int t = threadIdx.x;
    int b = blockIdx.x >> 7, j0 = (blockIdx.x & 127) << 1;
    int lane = t & 63, w = t >> 6;
    int n16 = lane & 15, quad = lane >> 4;

    // vector copy of pre-swizzled We: 2048 x 16 B
    {
        const intx4* srcW = (const intx4*)Wes;
        intx4* dstW = (intx4*)Wb;
#pragma unroll
        for (int it = 0; it < 8; ++it) dstW[t + it * 256] = srcW[t + it * 256];
    }
    float2 av2 = *(const float2*)&adj[(size_t)b * N_ * N_ + (size_t)t * N_ + j0];

    const size_t erow = (size_t)N_ * D_;
    const float* m2b = msg2 + (size_t)b * N_ * MID_;

    for (int jj = 0; jj < 2; ++jj) {
        int j = j0 + jj;
        float av = jj ? av2.y : av2.x;
        bool act = (av != 0.f);
        unsigned long long mk = __ballot(act);
        if (lane == 0) wcnt[w] = __popcll(mk);
        if (t < 128) C_sh[t] = C[((size_t)b * N_ + j) * MID_ + t];
        __syncthreads();   // also orders the Wb copy on jj==0
        int nact = wcnt[0] + wcnt[1] + wcnt[2] + wcnt[3];
        int base = 0;
        if (w > 0) base += wcnt[0];
        if (w > 1) base += wcnt[1];
        if (w > 2) base += wcnt[2];
        int pos = base + __popcll(mk & ((1ull << lane) - 1ull));
        if (act) { list_sh[pos] = (unsigned short)t; aval_sh[pos] = av; }
        __syncthreads();

        const float* ebase = e + (size_t)b * N_ * N_ * D_ + (size_t)j * D_ + quad * 8;

        floatx4 rm[8];
#pragma unroll
        for (int mt = 0; mt < 8; ++mt) rm[mt] = (floatx4)(-INFINITY);

        int nch = (nact + 15) >> 4;          // 16 active rows per chunk
        for (int c = w; c < nch; c += 8) {   // wave w owns chunk pair (c, c+4)
            int s0 = c * 16 + n16;
            int s1 = (c + 4) * 16 + n16;
            int i0 = 0, i1 = 0; float aw0 = 0.f, aw1 = 0.f;
            if (s0 < nact) { i0 = list_sh[s0]; aw0 = aval_sh[s0]; }
            if (s1 < nact) { i1 = list_sh[s1]; aw1 = aval_sh[s1]; }
            const float* r0 = ebase + (size_t)i0 * erow;
            const float* r1 = ebase + (size_t)i1 * erow;
            bf16x8 ef0[4], ef1[4];
#pragma unroll
            for (int q = 0; q < 4; ++q) {
                floatx4 a0 = *(const floatx4*)(r0 + q * 32);
                floatx4 b0 = *(const floatx4*)(r0 + q * 32 + 4);
                floatx4 a1 = *(const floatx4*)(r1 + q * 32);
                floatx4 b1 = *(const floatx4*)(r1 + q * 32 + 4);
                ef0[q] = cvt8(a0, b0);
                ef1[q] = cvt8(a1, b1);
            }
            const float* m2r0 = m2b + (size_t)i0 * MID_;
            const float* m2r1 = m2b + (size_t)i1 * MID_;
#pragma unroll 2
            for (int mt = 0; mt < 8; ++mt) {
                int m0 = mt * 16 + quad * 4;
                floatx4 c4 = *(const floatx4*)&C_sh[m0];
                floatx4 acc0 = c4, acc1 = c4;
#pragma unroll
                for (int ks = 0; ks < 4; ++ks) {
                    bf16x8 aW = *(const bf16x8*)&Wb[((ks * 8 + mt) * 64 + lane) * 8];
                    acc0 = mfma16(aW, ef0[ks], acc0);
                    acc1 = mfma16(aW, ef1[ks], acc1);
                }
                floatx4 m20 = *(const floatx4*)&m2r0[m0];
                floatx4 m21 = *(const floatx4*)&m2r1[m0];
#pragma unroll
                for (int r = 0; r < 4; ++r) {
                    float v0 = (acc0[r] + m20[r]) * aw0;
                    float v1 = (acc1[r] + m21[r]) * aw1;
                    rm[mt][r] = fmaxf(rm[mt][r], fmaxf(v0, v1));
                }
            }
        }

        // reduce over i-slots (n16 lanes) via xor-shuffles, then stash per-wave result
#pragma unroll
        for (int mt = 0; mt < 8; ++mt) {
#pragma unroll
            for (int r = 0; r < 4; ++r) {
                float v = rm[mt][r];
                v = fmaxf(v, __shfl_xor(v, 1, 64));
                v = fmaxf(v, __shfl_xor(v, 2, 64));
                v = fmaxf(v, __shfl_xor(v, 4, 64));
                v = fmaxf(v, __shfl_xor(v, 8, 64));
                rm[mt][r] = v;
            }
        }
        if (n16 == 0) {
#pragma unroll
            for (int mt = 0; mt < 8; ++mt)
                *(floatx4*)&wmax[w][mt * 16 + quad * 4] = rm[mt];
        }
        __syncthreads();

        int m = t & 127, h = t >> 7;
        if (t < 128) {
            float mx = fmaxf(fmaxf(wmax[0][m], wmax[1][m]), fmaxf(wmax[2][m], wmax[3][m]));
            if (nact < 256) mx = fmaxf(mx, 0.f);   // adj==0 rows contribute exact 0
            msgs_sh[m] = mx;
        }
        __syncthreads();

        // fused: ret = retA + msgs @ Wo2   (split-k over the two thread halves)
        float a2 = 0.f;
        for (int k = h * 64; k < h * 64 + 64; ++k)
            a2 += msgs_sh[k] * Wo2[k * MID_ + m];
        part[h][m] = a2;
        __syncthreads();
        if (t < 128) {
            int R = b * N_ + j;
            out[(size_t)R * MID_ + m] = retA[R * MID_ + m] + part[0][m] + part[1][m];
        }
        __syncthreads();   // protect lists/C_sh/part before next jj overwrites
    }
}

extern "C" void kernel_launch(void* const* d_in, const int* in_sizes, int n_in,
                              void* d_out, int out_size, void* d_ws, size_t ws_size,
                              hipStream_t stream) {
    (void)in_sizes; (void)n_in; (void)out_size; (void)ws_size;
    const float* hidden = (const float*)d_in[0];
    const float* nfeat  = (const float*)d_in[1];
    const float* e      = (const float*)d_in[2];
    const float* g      = (const float*)d_in[3];
    const float* adj    = (const float*)d_in[4];
    const float* W1  = (const float*)d_in[5];
    const float* b1  = (const float*)d_in[6];
    const float* W2  = (const float*)d_in[7];
    const float* b2  = (const float*)d_in[8];
    const float* We  = (const float*)d_in[9];
    const float* be  = (const float*)d_in[10];
    const float* Wg  = (const float*)d_in[11];
    const float* bg  = (const float*)d_in[12];
    const float* Wo1 = (const float*)d_in[13];
    const float* bo1 = (const float*)d_in[14];
    const float* Wo2 = (const float*)d_in[15];
    const float* bo2 = (const float*)d_in[16];
    float* outp = (float*)d_out;

    float* ws = (float*)d_ws;
    __bf16* Wpre = (__bf16*)ws;              // 114688 bf16 = 229376 B
    float* C    = ws + 57344;                // 262144 floats
    float* msg2 = C + 262144;                // 262144
    float* retA = msg2 + 262144;             // 262144  (~3.4 MB total)

    kW<<<56, 256, 0, stream>>>(W1, W2, Wo1, We, Wpre);
    kA<<<dim3(32, 3), 256, 0, stream>>>(nfeat, hidden, Wpre,
                                        g, Wg, bg, b1, be, b2, bo1, bo2,
                                        C, msg2, retA);
    kB<<<1024, 256, 0, stream>>>(e, Wpre + 98304, adj, C, msg2, retA, Wo2, outp);
}

// Round 5
// 399.879 us; speedup vs baseline: 1.0707x; 1.0707x over previous
//
#include <hip/hip_runtime.h>
#include <stdint.h>

#define B_   8
#define N_   256
#define D_   128
#define MID_ 128
#define FEAT_ 256

typedef __attribute__((ext_vector_type(4))) float  floatx4;
typedef __attribute__((ext_vector_type(4))) int    intx4;
typedef __attribute__((ext_vector_type(8))) __bf16 bf16x8;

__device__ __forceinline__ floatx4 mfma16(bf16x8 a, bf16x8 b, floatx4 c) {
    return __builtin_amdgcn_mfma_f32_16x16x32_bf16(a, b, c, 0, 0, 0);
}

// HW bf16 convert (compiler emits v_cvt_pk_bf16_f32 on gfx950), RNE.
__device__ __forceinline__ bf16x8 cvt8(floatx4 a, floatx4 b) {
    bf16x8 r;
    r[0] = (__bf16)a[0]; r[1] = (__bf16)a[1]; r[2] = (__bf16)a[2]; r[3] = (__bf16)a[3];
    r[4] = (__bf16)b[0]; r[5] = (__bf16)b[1]; r[6] = (__bf16)b[2]; r[7] = (__bf16)b[3];
    return r;
}

// ---------------- kernel W: pre-swizzle all weights to bf16 LDS-image layout ----------------
// dst elem index for (k,m): (((k>>5)*8+(m>>4))*64 + ((k>>3)&3)*16 + (m&15))*8 + (k&7)
// Each thread: 8 coalesced f32 loads (j = k&7), one contiguous 16-B bf16x8 store.
__global__ void __launch_bounds__(256)
kW(const float* __restrict__ W1, const float* __restrict__ W2,
   const float* __restrict__ Wo1, const float* __restrict__ We,
   __bf16* __restrict__ dst) {
    int t = threadIdx.x;
    int g = blockIdx.x * 2 + (t >> 7);   // global k-group 0..111
    int m = t & 127;
    const float* src; int kg; int off;
    if (g < 32)      { src = W1;  kg = g;      off = 0; }
    else if (g < 64) { src = W2;  kg = g - 32; off = 32768; }
    else if (g < 96) { src = Wo1; kg = g - 64; off = 65536; }
    else             { src = We;  kg = g - 96; off = 98304; }
    bf16x8 r;
#pragma unroll
    for (int jv = 0; jv < 8; ++jv) r[jv] = (__bf16)src[(kg * 8 + jv) * MID_ + m];
    int base = (((kg >> 2) * 8 + (m >> 4)) * 64 + (kg & 3) * 16 + (m & 15)) * 8;
    *(bf16x8*)&dst[off + base] = r;
}

// ---------------- kernel A: per-node GEMMs via MFMA (bf16) + fused gplus ----------------
// grid (32 row-tiles of 64, 3 weights). A = W^T (pre-swizzled, vector-copied to LDS).
// wid 0: C = feat@W1 + (g@Wg+bg+b1+be) ; wid 1: msg2 = feat@W2 + b2 ; wid 2: retA = feat@Wo1+bo1+bo2
__global__ void __launch_bounds__(256)
kA(const float* __restrict__ nfeat, const float* __restrict__ hidden,
   const __bf16* __restrict__ Wpre,
   const float* __restrict__ g, const float* __restrict__ Wg,
   const float* __restrict__ bg, const float* __restrict__ b1,
   const float* __restrict__ be, const float* __restrict__ b2,
   const float* __restrict__ bo1, const float* __restrict__ bo2,
   float* __restrict__ C, float* __restrict__ msg2, float* __restrict__ retA) {
    __shared__ __bf16 Wb[8 * 8 * 64 * 8];   // [ks][mt][lane][jj], 64 KB
    __shared__ float gp_part[2][MID_];
    __shared__ float gp_sh[MID_];
    int t = threadIdx.x;
    int wid = blockIdx.y;
    // vector copy of pre-swizzled bf16 weights: 4096 x 16 B
    {
        const intx4* srcW = (const intx4*)(Wpre + (size_t)wid * 32768);
        intx4* dstW = (intx4*)Wb;
#pragma unroll
        for (int it = 0; it < 16; ++it) dstW[t + it * 256] = srcW[t + it * 256];
    }
    // fused kG: gplus[b] = g[b]@Wg + bg + b1 + be  (block-uniform batch, split-k halves)
    int bblk = blockIdx.x >> 2;             // 4 row-tiles per batch
    if (wid == 0) {
        int m = t & 127, h = t >> 7;
        const float* gr = g + bblk * D_;
        float a = 0.f;
        for (int k = h * 64; k < h * 64 + 64; ++k)
            a += gr[k] * Wg[k * MID_ + m];
        gp_part[h][m] = a;
    }
    __syncthreads();
    if (wid == 0 && t < 128)
        gp_sh[t] = gp_part[0][t] + gp_part[1][t] + bg[t] + b1[t] + be[t];
    __syncthreads();

    int lane = t & 63, w = t >> 6;
    int n16 = lane & 15, quad = lane >> 4;
    int R = blockIdx.x * 64 + w * 16 + n16;   // feat row (tile never crosses batch)
    const float* frow0 = nfeat  + (size_t)R * D_ + quad * 8;
    const float* frow1 = hidden + (size_t)R * D_ + quad * 8;

    bf16x8 bfrag[8];
#pragma unroll
    for (int ks = 0; ks < 8; ++ks) {
        const float* p = (ks < 4) ? (frow0 + ks * 32) : (frow1 + (ks - 4) * 32);
        floatx4 v0 = *(const floatx4*)p;
        floatx4 v1 = *(const floatx4*)(p + 4);
        bfrag[ks] = cvt8(v0, v1);
    }

    float* outp = (wid == 0) ? C : ((wid == 1) ? msg2 : retA);
#pragma unroll 2
    for (int mt = 0; mt < 8; ++mt) {
        floatx4 acc = (floatx4)0.f;
#pragma unroll
        for (int ks = 0; ks < 8; ++ks) {
            bf16x8 a = *(const bf16x8*)&Wb[((ks * 8 + mt) * 64 + lane) * 8];
            acc = mfma16(a, bfrag[ks], acc);
        }
        int m0 = mt * 16 + quad * 4;
        floatx4 add;
        if (wid == 0)      add = *(const floatx4*)&gp_sh[m0];
        else if (wid == 1) add = *(const floatx4*)&b2[m0];
        else {
            floatx4 x = *(const floatx4*)&bo1[m0];
            floatx4 y = *(const floatx4*)&bo2[m0];
            add = x + y;
        }
        *(floatx4*)&outp[(size_t)R * MID_ + m0] = acc + add;
    }
}

// ---------------- kernel B: fused msg_e GEMM + broadcast-add + mask-max + out ----------------
// one block per (b, j) [V1 geometry: 2048 blocks, best measured]. adj is {0,1}: compact the
// active-i list, load/compute only those e-rows. NEW: next chunk's e-rows are prefetched
// into registers while the current chunk's MFMAs run (hides ~900-cyc HBM latency at 4
// waves/SIMD). Padding slots contribute exact 0 (legal when nact<256; fmax covers rest).
__global__ void __launch_bounds__(256, 4)
kB(const float* __restrict__ e, const __bf16* __restrict__ Wes,
   const float* __restrict__ adj, const float* __restrict__ C,
   const float* __restrict__ msg2, const float* __restrict__ retA,
   const float* __restrict__ Wo2, float* __restrict__ out) {
    __shared__ __bf16 Wb[4 * 8 * 64 * 8];   // [ks][mt][lane][jj], 32 KB
    __shared__ float C_sh[MID_];
    __shared__ float wmax[4][MID_];
    __shared__ float msgs_sh[MID_];
    __shared__ float part[2][MID_];
    __shared__ unsigned short list_sh[N_];
    __shared__ float aval_sh[N_];
    __shared__ int wcnt[4];

    int t = threadIdx.x;
    int b = blockIdx.x >> 8, j = blockIdx.x & 255;
    int lane = t & 63, w = t >> 6;
    int n16 = lane & 15, quad = lane >> 4;

    // vector copy of pre-swizzled We: 2048 x 16 B
    {
        const intx4* srcW = (const intx4*)Wes;
        intx4* dstW = (intx4*)Wb;
#pragma unroll
        for (int it = 0; it < 8; ++it) dstW[t + it * 256] = srcW[t + it * 256];
    }
    // adj compaction: thread t owns row i=t of this column j
    float av = adj[(size_t)b * N_ * N_ + (size_t)t * N_ + j];
    bool act = (av != 0.f);
    unsigned long long mk = __ballot(act);
    if (lane == 0) wcnt[w] = __popcll(mk);
    if (t < 128) C_sh[t] = C[((size_t)b * N_ + j) * MID_ + t];
    __syncthreads();   // also orders the Wb copy
    int nact = wcnt[0] + wcnt[1] + wcnt[2] + wcnt[3];
    int base = 0;
    if (w > 0) base += wcnt[0];
    if (w > 1) base += wcnt[1];
    if (w > 2) base += wcnt[2];
    int pos = base + __popcll(mk & ((1ull << lane) - 1ull));
    if (act) { list_sh[pos] = (unsigned short)t; aval_sh[pos] = av; }
    __syncthreads();

    const size_t erow = (size_t)N_ * D_;
    const float* ebase = e + (size_t)b * N_ * N_ * D_ + (size_t)j * D_ + quad * 8;
    const float* m2b   = msg2 + (size_t)b * N_ * MID_;

    floatx4 rm[8];
#pragma unroll
    for (int mt = 0; mt < 8; ++mt) rm[mt] = (floatx4)(-INFINITY);

    int nch = (nact + 15) >> 4;          // 16 active rows per chunk

    // prologue: fetch chunk c=w's row into v
    int idxn = 0; float awn = 0.f;
    {
        int slot = w * 16 + n16;
        if (w < nch && slot < nact) { idxn = list_sh[slot]; awn = aval_sh[slot]; }
    }
    floatx4 v[8];
    {
        const float* rowp = ebase + (size_t)idxn * erow;
#pragma unroll
        for (int q = 0; q < 4; ++q) {
            v[2 * q]     = *(const floatx4*)(rowp + q * 32);
            v[2 * q + 1] = *(const floatx4*)(rowp + q * 32 + 4);
        }
    }

    for (int c = w; c < nch; c += 4) {
        // 1) convert current rows (frees v before the prefetch goes live)
        bf16x8 ef[4];
#pragma unroll
        for (int q = 0; q < 4; ++q) ef[q] = cvt8(v[2 * q], v[2 * q + 1]);
        float aw = awn;
        const float* m2r = m2b + (size_t)idxn * MID_;

        // 2) issue next chunk's loads (exact addresses from list_sh; clamped tail reads row 0)
        int cn = c + 4;
        idxn = 0; awn = 0.f;
        {
            int slot = cn * 16 + n16;
            if (cn < nch && slot < nact) { idxn = list_sh[slot]; awn = aval_sh[slot]; }
        }
        {
            const float* rowp = ebase + (size_t)idxn * erow;
#pragma unroll
            for (int q = 0; q < 4; ++q) {
                v[2 * q]     = *(const floatx4*)(rowp + q * 32);
                v[2 * q + 1] = *(const floatx4*)(rowp + q * 32 + 4);
            }
        }

        // 3) MFMA current chunk (HBM latency of step 2 hides under this)
#pragma unroll 2
        for (int mt = 0; mt < 8; ++mt) {
            int m0 = mt * 16 + quad * 4;
            floatx4 m2v = *(const floatx4*)&m2r[m0];
            floatx4 acc = *(const floatx4*)&C_sh[m0];   // C folded into acc init
#pragma unroll
            for (int ks = 0; ks < 4; ++ks) {
                bf16x8 aW = *(const bf16x8*)&Wb[((ks * 8 + mt) * 64 + lane) * 8];
                acc = mfma16(aW, ef[ks], acc);
            }
#pragma unroll
            for (int r = 0; r < 4; ++r)
                rm[mt][r] = fmaxf(rm[mt][r], (acc[r] + m2v[r]) * aw);
        }
    }

    // reduce over i-slots (n16 lanes) via xor-shuffles, then stash per-wave result
#pragma unroll
    for (int mt = 0; mt < 8; ++mt) {
#pragma unroll
        for (int r = 0; r < 4; ++r) {
            float vv = rm[mt][r];
            vv = fmaxf(vv, __shfl_xor(vv, 1, 64));
            vv = fmaxf(vv, __shfl_xor(vv, 2, 64));
            vv = fmaxf(vv, __shfl_xor(vv, 4, 64));
            vv = fmaxf(vv, __shfl_xor(vv, 8, 64));
            rm[mt][r] = vv;
        }
    }
    if (n16 == 0) {
#pragma unroll
        for (int mt = 0; mt < 8; ++mt)
            *(floatx4*)&wmax[w][mt * 16 + quad * 4] = rm[mt];
    }
    __syncthreads();

    int m = t & 127, h = t >> 7;
    if (t < 128) {
        float mx = fmaxf(fmaxf(wmax[0][m], wmax[1][m]), fmaxf(wmax[2][m], wmax[3][m]));
        if (nact < 256) mx = fmaxf(mx, 0.f);   // adj==0 rows contribute exact 0
        msgs_sh[m] = mx;
    }
    __syncthreads();

    // fused: ret = retA + msgs @ Wo2   (split-k over the two thread halves)
    float a2 = 0.f;
    for (int k = h * 64; k < h * 64 + 64; ++k)
        a2 += msgs_sh[k] * Wo2[k * MID_ + m];
    part[h][m] = a2;
    __syncthreads();
    if (t < 128) {
        int R = b * N_ + j;
        out[(size_t)R * MID_ + m] = retA[R * MID_ + m] + part[0][m] + part[1][m];
    }
}

extern "C" void kernel_launch(void* const* d_in, const int* in_sizes, int n_in,
                              void* d_out, int out_size, void* d_ws, size_t ws_size,
                              hipStream_t stream) {
    (void)in_sizes; (void)n_in; (void)out_size; (void)ws_size;
    const float* hidden = (const float*)d_in[0];
    const float* nfeat  = (const float*)d_in[1];
    const float* e      = (const float*)d_in[2];
    const float* g      = (const float*)d_in[3];
    const float* adj    = (const float*)d_in[4];
    const float* W1  = (const float*)d_in[5];
    const float* b1  = (const float*)d_in[6];
    const float* W2  = (const float*)d_in[7];
    const float* b2  = (const float*)d_in[8];
    const float* We  = (const float*)d_in[9];
    const float* be  = (const float*)d_in[10];
    const float* Wg  = (const float*)d_in[11];
    const float* bg  = (const float*)d_in[12];
    const float* Wo1 = (const float*)d_in[13];
    const float* bo1 = (const float*)d_in[14];
    const float* Wo2 = (const float*)d_in[15];
    const float* bo2 = (const float*)d_in[16];
    float* outp = (float*)d_out;

    float* ws = (float*)d_ws;
    __bf16* Wpre = (__bf16*)ws;              // 114688 bf16 = 229376 B
    float* C    = ws + 57344;                // 262144 floats
    float* msg2 = C + 262144;                // 262144
    float* retA = msg2 + 262144;             // 262144  (~3.4 MB total)

    kW<<<56, 256, 0, stream>>>(W1, W2, Wo1, We, Wpre);
    kA<<<dim3(32, 3), 256, 0, stream>>>(nfeat, hidden, Wpre,
                                        g, Wg, bg, b1, be, b2, bo1, bo2,
                                        C, msg2, retA);
    kB<<<2048, 256, 0, stream>>>(e, Wpre + 98304, adj, C, msg2, retA, Wo2, outp);
}

// Round 6
// 392.020 us; speedup vs baseline: 1.0922x; 1.0200x over previous
//
#include <hip/hip_runtime.h>
#include <stdint.h>

#define B_   8
#define N_   256
#define D_   128
#define MID_ 128
#define FEAT_ 256

typedef __attribute__((ext_vector_type(4))) float  floatx4;
typedef __attribute__((ext_vector_type(4))) int    intx4;
typedef __attribute__((ext_vector_type(8))) __bf16 bf16x8;

__device__ __forceinline__ floatx4 mfma16(bf16x8 a, bf16x8 b, floatx4 c) {
    return __builtin_amdgcn_mfma_f32_16x16x32_bf16(a, b, c, 0, 0, 0);
}

// HW bf16 convert (compiler emits v_cvt_pk_bf16_f32 on gfx950), RNE.
__device__ __forceinline__ bf16x8 cvt8(floatx4 a, floatx4 b) {
    bf16x8 r;
    r[0] = (__bf16)a[0]; r[1] = (__bf16)a[1]; r[2] = (__bf16)a[2]; r[3] = (__bf16)a[3];
    r[4] = (__bf16)b[0]; r[5] = (__bf16)b[1]; r[6] = (__bf16)b[2]; r[7] = (__bf16)b[3];
    return r;
}

// ---------------- kernel W: pre-swizzle all weights to bf16 LDS-image layout ----------------
// dst elem index for (k,m): (((k>>5)*8+(m>>4))*64 + ((k>>3)&3)*16 + (m&15))*8 + (k&7)
// Each thread: 8 coalesced f32 loads (j = k&7), one contiguous 16-B bf16x8 store.
__global__ void __launch_bounds__(256)
kW(const float* __restrict__ W1, const float* __restrict__ W2,
   const float* __restrict__ Wo1, const float* __restrict__ We,
   __bf16* __restrict__ dst) {
    int t = threadIdx.x;
    int g = blockIdx.x * 2 + (t >> 7);   // global k-group 0..111
    int m = t & 127;
    const float* src; int kg; int off;
    if (g < 32)      { src = W1;  kg = g;      off = 0; }
    else if (g < 64) { src = W2;  kg = g - 32; off = 32768; }
    else if (g < 96) { src = Wo1; kg = g - 64; off = 65536; }
    else             { src = We;  kg = g - 96; off = 98304; }
    bf16x8 r;
#pragma unroll
    for (int jv = 0; jv < 8; ++jv) r[jv] = (__bf16)src[(kg * 8 + jv) * MID_ + m];
    int base = (((kg >> 2) * 8 + (m >> 4)) * 64 + (kg & 3) * 16 + (m & 15)) * 8;
    *(bf16x8*)&dst[off + base] = r;
}

// ---------------- kernel A: per-node GEMMs via MFMA (bf16) + fused gplus ----------------
// grid (32 row-tiles of 64, 3 weights). A = W^T (pre-swizzled, vector-copied to LDS).
// wid 0: C = feat@W1 + (g@Wg+bg+b1+be) ; wid 1: msg2 = feat@W2 + b2 ; wid 2: retA = feat@Wo1+bo1+bo2
__global__ void __launch_bounds__(256)
kA(const float* __restrict__ nfeat, const float* __restrict__ hidden,
   const __bf16* __restrict__ Wpre,
   const float* __restrict__ g, const float* __restrict__ Wg,
   const float* __restrict__ bg, const float* __restrict__ b1,
   const float* __restrict__ be, const float* __restrict__ b2,
   const float* __restrict__ bo1, const float* __restrict__ bo2,
   float* __restrict__ C, float* __restrict__ msg2, float* __restrict__ retA) {
    __shared__ __bf16 Wb[8 * 8 * 64 * 8];   // [ks][mt][lane][jj], 64 KB
    __shared__ float gp_part[2][MID_];
    __shared__ float gp_sh[MID_];
    int t = threadIdx.x;
    int wid = blockIdx.y;
    // vector copy of pre-swizzled bf16 weights: 4096 x 16 B
    {
        const intx4* srcW = (const intx4*)(Wpre + (size_t)wid * 32768);
        intx4* dstW = (intx4*)Wb;
#pragma unroll
        for (int it = 0; it < 16; ++it) dstW[t + it * 256] = srcW[t + it * 256];
    }
    // fused kG: gplus[b] = g[b]@Wg + bg + b1 + be  (block-uniform batch, split-k halves)
    int bblk = blockIdx.x >> 2;             // 4 row-tiles per batch
    if (wid == 0) {
        int m = t & 127, h = t >> 7;
        const float* gr = g + bblk * D_;
        float a = 0.f;
        for (int k = h * 64; k < h * 64 + 64; ++k)
            a += gr[k] * Wg[k * MID_ + m];
        gp_part[h][m] = a;
    }
    __syncthreads();
    if (wid == 0 && t < 128)
        gp_sh[t] = gp_part[0][t] + gp_part[1][t] + bg[t] + b1[t] + be[t];
    __syncthreads();

    int lane = t & 63, w = t >> 6;
    int n16 = lane & 15, quad = lane >> 4;
    int R = blockIdx.x * 64 + w * 16 + n16;   // feat row (tile never crosses batch)
    const float* frow0 = nfeat  + (size_t)R * D_ + quad * 8;
    const float* frow1 = hidden + (size_t)R * D_ + quad * 8;

    bf16x8 bfrag[8];
#pragma unroll
    for (int ks = 0; ks < 8; ++ks) {
        const float* p = (ks < 4) ? (frow0 + ks * 32) : (frow1 + (ks - 4) * 32);
        floatx4 v0 = *(const floatx4*)p;
        floatx4 v1 = *(const floatx4*)(p + 4);
        bfrag[ks] = cvt8(v0, v1);
    }

    float* outp = (wid == 0) ? C : ((wid == 1) ? msg2 : retA);
#pragma unroll 2
    for (int mt = 0; mt < 8; ++mt) {
        floatx4 acc = (floatx4)0.f;
#pragma unroll
        for (int ks = 0; ks < 8; ++ks) {
            bf16x8 a = *(const bf16x8*)&Wb[((ks * 8 + mt) * 64 + lane) * 8];
            acc = mfma16(a, bfrag[ks], acc);
        }
        int m0 = mt * 16 + quad * 4;
        floatx4 add;
        if (wid == 0)      add = *(const floatx4*)&gp_sh[m0];
        else if (wid == 1) add = *(const floatx4*)&b2[m0];
        else {
            floatx4 x = *(const floatx4*)&bo1[m0];
            floatx4 y = *(const floatx4*)&bo2[m0];
            add = x + y;
        }
        *(floatx4*)&outp[(size_t)R * MID_ + m0] = acc + add;
    }
}

// ---------------- kernel B: fused msg_e GEMM + broadcast-add + mask-max + out ----------------
// one block per (b, j) [2048 blocks, best measured]. adj is {0,1}: compact the active-i
// list, load/compute only those e-rows. Wave w owns chunks {w, w+4, w+8, ...}; its two
// typical chunks are processed as a PAIR so each Wb ds_read_b128 feeds 2 MFMAs (halves the
// LDS-read critical path) with 16 e-loads in flight. Tail chunks processed serially.
// Padding slots contribute exact 0 (legal when nact<256; fmax(mx,0) covers the rest).
__global__ void __launch_bounds__(256, 4)
kB(const float* __restrict__ e, const __bf16* __restrict__ Wes,
   const float* __restrict__ adj, const float* __restrict__ C,
   const float* __restrict__ msg2, const float* __restrict__ retA,
   const float* __restrict__ Wo2, float* __restrict__ out) {
    __shared__ __bf16 Wb[4 * 8 * 64 * 8];   // [ks][mt][lane][jj], 32 KB
    __shared__ float C_sh[MID_];
    __shared__ float wmax[4][MID_];
    __shared__ float msgs_sh[MID_];
    __shared__ float part[2][MID_];
    __shared__ unsigned short list_sh[N_];
    __shared__ float aval_sh[N_];
    __shared__ int wcnt[4];

    int t = threadIdx.x;
    int b = blockIdx.x >> 8, j = blockIdx.x & 255;
    int lane = t & 63, w = t >> 6;
    int n16 = lane & 15, quad = lane >> 4;

    // vector copy of pre-swizzled We: 2048 x 16 B
    {
        const intx4* srcW = (const intx4*)Wes;
        intx4* dstW = (intx4*)Wb;
#pragma unroll
        for (int it = 0; it < 8; ++it) dstW[t + it * 256] = srcW[t + it * 256];
    }
    // adj compaction: thread t owns row i=t of this column j
    float av = adj[(size_t)b * N_ * N_ + (size_t)t * N_ + j];
    bool act = (av != 0.f);
    unsigned long long mk = __ballot(act);
    if (lane == 0) wcnt[w] = __popcll(mk);
    if (t < 128) C_sh[t] = C[((size_t)b * N_ + j) * MID_ + t];
    __syncthreads();   // also orders the Wb copy
    int nact = wcnt[0] + wcnt[1] + wcnt[2] + wcnt[3];
    int base = 0;
    if (w > 0) base += wcnt[0];
    if (w > 1) base += wcnt[1];
    if (w > 2) base += wcnt[2];
    int pos = base + __popcll(mk & ((1ull << lane) - 1ull));
    if (act) { list_sh[pos] = (unsigned short)t; aval_sh[pos] = av; }
    __syncthreads();

    const size_t erow = (size_t)N_ * D_;
    const float* ebase = e + (size_t)b * N_ * N_ * D_ + (size_t)j * D_ + quad * 8;
    const float* m2b   = msg2 + (size_t)b * N_ * MID_;

    floatx4 rm[8];
#pragma unroll
    for (int mt = 0; mt < 8; ++mt) rm[mt] = (floatx4)(-INFINITY);

    int nch = (nact + 15) >> 4;          // 16 active rows per chunk
    int c = w;

    // paired chunks (typical case: exactly one pair per wave at nact~128)
    for (; c + 4 < nch; c += 8) {
        int s0 = c * 16 + n16, s1 = (c + 4) * 16 + n16;
        int i0 = 0, i1 = 0; float aw0 = 0.f, aw1 = 0.f;
        if (s0 < nact) { i0 = list_sh[s0]; aw0 = aval_sh[s0]; }
        if (s1 < nact) { i1 = list_sh[s1]; aw1 = aval_sh[s1]; }
        const float* r0 = ebase + (size_t)i0 * erow;
        const float* r1 = ebase + (size_t)i1 * erow;
        floatx4 vA[8], vB[8];
#pragma unroll
        for (int q = 0; q < 4; ++q) {      // 16 loads in flight
            vA[2 * q]     = *(const floatx4*)(r0 + q * 32);
            vA[2 * q + 1] = *(const floatx4*)(r0 + q * 32 + 4);
            vB[2 * q]     = *(const floatx4*)(r1 + q * 32);
            vB[2 * q + 1] = *(const floatx4*)(r1 + q * 32 + 4);
        }
        bf16x8 ef0[4], ef1[4];
#pragma unroll
        for (int q = 0; q < 4; ++q) {
            ef0[q] = cvt8(vA[2 * q], vA[2 * q + 1]);
            ef1[q] = cvt8(vB[2 * q], vB[2 * q + 1]);
        }
        const float* m2r0 = m2b + (size_t)i0 * MID_;
        const float* m2r1 = m2b + (size_t)i1 * MID_;
#pragma unroll 2
        for (int mt = 0; mt < 8; ++mt) {
            int m0 = mt * 16 + quad * 4;
            floatx4 c4 = *(const floatx4*)&C_sh[m0];
            floatx4 acc0 = c4, acc1 = c4;
#pragma unroll
            for (int ks = 0; ks < 4; ++ks) {
                bf16x8 aW = *(const bf16x8*)&Wb[((ks * 8 + mt) * 64 + lane) * 8];
                acc0 = mfma16(aW, ef0[ks], acc0);
                acc1 = mfma16(aW, ef1[ks], acc1);
            }
            floatx4 m20 = *(const floatx4*)&m2r0[m0];
            floatx4 m21 = *(const floatx4*)&m2r1[m0];
#pragma unroll
            for (int r = 0; r < 4; ++r) {
                float v0 = (acc0[r] + m20[r]) * aw0;
                float v1 = (acc1[r] + m21[r]) * aw1;
                rm[mt][r] = fmaxf(rm[mt][r], fmaxf(v0, v1));
            }
        }
    }

    // serial tail chunks
    for (; c < nch; c += 4) {
        int slot = c * 16 + n16;
        int idx = 0; float aw = 0.f;
        if (slot < nact) { idx = list_sh[slot]; aw = aval_sh[slot]; }
        const float* rowp = ebase + (size_t)idx * erow;
        floatx4 v[8];
#pragma unroll
        for (int q = 0; q < 4; ++q) {
            v[2 * q]     = *(const floatx4*)(rowp + q * 32);
            v[2 * q + 1] = *(const floatx4*)(rowp + q * 32 + 4);
        }
        bf16x8 ef[4];
#pragma unroll
        for (int q = 0; q < 4; ++q) ef[q] = cvt8(v[2 * q], v[2 * q + 1]);
        const float* m2r = m2b + (size_t)idx * MID_;
#pragma unroll 2
        for (int mt = 0; mt < 8; ++mt) {
            int m0 = mt * 16 + quad * 4;
            floatx4 m2v = *(const floatx4*)&m2r[m0];
            floatx4 acc = *(const floatx4*)&C_sh[m0];
#pragma unroll
            for (int ks = 0; ks < 4; ++ks) {
                bf16x8 aW = *(const bf16x8*)&Wb[((ks * 8 + mt) * 64 + lane) * 8];
                acc = mfma16(aW, ef[ks], acc);
            }
#pragma unroll
            for (int r = 0; r < 4; ++r)
                rm[mt][r] = fmaxf(rm[mt][r], (acc[r] + m2v[r]) * aw);
        }
    }

    // reduce over i-slots (n16 lanes) via xor-shuffles, then stash per-wave result
#pragma unroll
    for (int mt = 0; mt < 8; ++mt) {
#pragma unroll
        for (int r = 0; r < 4; ++r) {
            float vv = rm[mt][r];
            vv = fmaxf(vv, __shfl_xor(vv, 1, 64));
            vv = fmaxf(vv, __shfl_xor(vv, 2, 64));
            vv = fmaxf(vv, __shfl_xor(vv, 4, 64));
            vv = fmaxf(vv, __shfl_xor(vv, 8, 64));
            rm[mt][r] = vv;
        }
    }
    if (n16 == 0) {
#pragma unroll
        for (int mt = 0; mt < 8; ++mt)
            *(floatx4*)&wmax[w][mt * 16 + quad * 4] = rm[mt];
    }
    __syncthreads();

    int m = t & 127, h = t >> 7;
    if (t < 128) {
        float mx = fmaxf(fmaxf(wmax[0][m], wmax[1][m]), fmaxf(wmax[2][m], wmax[3][m]));
        if (nact < 256) mx = fmaxf(mx, 0.f);   // adj==0 rows contribute exact 0
        msgs_sh[m] = mx;
    }
    __syncthreads();

    // fused: ret = retA + msgs @ Wo2   (split-k over the two thread halves)
    float a2 = 0.f;
    for (int k = h * 64; k < h * 64 + 64; ++k)
        a2 += msgs_sh[k] * Wo2[k * MID_ + m];
    part[h][m] = a2;
    __syncthreads();
    if (t < 128) {
        int R = b * N_ + j;
        out[(size_t)R * MID_ + m] = retA[R * MID_ + m] + part[0][m] + part[1][m];
    }
}

extern "C" void kernel_launch(void* const* d_in, const int* in_sizes, int n_in,
                              void* d_out, int out_size, void* d_ws, size_t ws_size,
                              hipStream_t stream) {
    (void)in_sizes; (void)n_in; (void)out_size; (void)ws_size;
    const float* hidden = (const float*)d_in[0];
    const float* nfeat  = (const float*)d_in[1];
    const float* e      = (const float*)d_in[2];
    const float* g      = (const float*)d_in[3];
    const float* adj    = (const float*)d_in[4];
    const float* W1  = (const float*)d_in[5];
    const float* b1  = (const float*)d_in[6];
    const float* W2  = (const float*)d_in[7];
    const float* b2  = (const float*)d_in[8];
    const float* We  = (const float*)d_in[9];
    const float* be  = (const float*)d_in[10];
    const float* Wg  = (const float*)d_in[11];
    const float* bg  = (const float*)d_in[12];
    const float* Wo1 = (const float*)d_in[13];
    const float* bo1 = (const float*)d_in[14];
    const float* Wo2 = (const float*)d_in[15];
    const float* bo2 = (const float*)d_in[16];
    float* outp = (float*)d_out;

    float* ws = (float*)d_ws;
    __bf16* Wpre = (__bf16*)ws;              // 114688 bf16 = 229376 B
    float* C    = ws + 57344;                // 262144 floats
    float* msg2 = C + 262144;                // 262144
    float* retA = msg2 + 262144;             // 262144  (~3.4 MB total)

    kW<<<56, 256, 0, stream>>>(W1, W2, Wo1, We, Wpre);
    kA<<<dim3(32, 3), 256, 0, stream>>>(nfeat, hidden, Wpre,
                                        g, Wg, bg, b1, be, b2, bo1, bo2,
                                        C, msg2, retA);
    kB<<<2048, 256, 0, stream>>>(e, Wpre + 98304, adj, C, msg2, retA, Wo2, outp);
}